// Round 1
// baseline (245.819 us; speedup 1.0000x reference)
//
#include <hip/hip_runtime.h>
#include <hip/hip_bf16.h>

// Problem geometry (fixed by reference): B=16, Lq=Lk=2048, D=Dv=64, fp32.
// Outputs concatenated: out [16,2048,64] then w [16,2048,2048].
#define B_ 16
#define L_ 2048
#define D_ 64
#define TQ 64      // q-rows per block
#define TK 128     // key tile
#define LDSP (D_ + 4)   // padded LDS row stride (floats); keeps 16B alignment
#define NROWS (B_ * L_)

// ---------------------------------------------------------------------------
// Kernel A: fused QK^T (fp32, LDS-tiled) + online sum-exp + top-4 tracking +
// zero-fill of dense w. Per row, writes {renormalized top-3 weights, indices}
// to workspace.
// Thread layout: 256 threads; tr = tid>>4 owns rows 4tr..4tr+3; tc = tid&15
// owns keys ≡ tc (mod 16). Micro-tile 4 rows x 8 keys per thread.
// ---------------------------------------------------------------------------
__global__ __launch_bounds__(256)
void sdpa_score_stats(const float* __restrict__ q,
                      const float* __restrict__ k,
                      float* __restrict__ wout,      // [B_*L_*L_] (dense w)
                      float* __restrict__ wsv,       // [NROWS*4] weights
                      int*   __restrict__ wsi)       // [NROWS*4] indices
{
    __shared__ float Qs[TQ][LDSP];
    __shared__ float Ks[TK][LDSP];

    const int b    = blockIdx.y;
    const int rt   = blockIdx.x;
    const int tid  = threadIdx.x;
    const int tc   = tid & 15;
    const int tr   = tid >> 4;
    const int row0 = rt * TQ;

    const float* qb = q + (size_t)b * L_ * D_;
    const float* kb = k + (size_t)b * L_ * D_;
    float* wb = wout + (size_t)b * L_ * L_ + (size_t)row0 * L_;

    // Stage Q tile, pre-scaled by 1/TEMP = 1/8 (exact in fp32).
    #pragma unroll
    for (int it = 0; it < (TQ * D_) / (4 * 256); ++it) {
        int f = it * 256 + tid;
        int r = f >> 4;
        int c = (f & 15) * 4;
        float4 val = *reinterpret_cast<const float4*>(qb + (size_t)(row0 + r) * D_ + c);
        val.x *= 0.125f; val.y *= 0.125f; val.z *= 0.125f; val.w *= 0.125f;
        *reinterpret_cast<float4*>(&Qs[r][c]) = val;
    }

    // Per-thread running stats for 4 rows: sum of exp(s), sorted top-4 (desc).
    float Zacc[4] = {0.f, 0.f, 0.f, 0.f};
    float tv[4][4];
    int   ti[4][4];
    #pragma unroll
    for (int i = 0; i < 4; ++i)
        #pragma unroll
        for (int t = 0; t < 4; ++t) { tv[i][t] = -3.0e38f; ti[i][t] = 0; }

    for (int kt = 0; kt < L_ / TK; ++kt) {
        __syncthreads();   // Q ready (kt=0) / previous tile's compute done
        #pragma unroll
        for (int it = 0; it < (TK * D_) / (4 * 256); ++it) {
            int f = it * 256 + tid;
            int r = f >> 4;
            int c = (f & 15) * 4;
            *reinterpret_cast<float4*>(&Ks[r][c]) =
                *reinterpret_cast<const float4*>(kb + (size_t)(kt * TK + r) * D_ + c);
        }
        __syncthreads();

        float acc[4][8];
        #pragma unroll
        for (int i = 0; i < 4; ++i)
            #pragma unroll
            for (int j = 0; j < 8; ++j) acc[i][j] = 0.f;

        #pragma unroll 4
        for (int d = 0; d < D_; d += 4) {
            float4 qv[4];
            float4 kv[8];
            #pragma unroll
            for (int i = 0; i < 4; ++i)
                qv[i] = *reinterpret_cast<const float4*>(&Qs[tr * 4 + i][d]);
            #pragma unroll
            for (int j = 0; j < 8; ++j)
                kv[j] = *reinterpret_cast<const float4*>(&Ks[tc + 16 * j][d]);
            #pragma unroll
            for (int i = 0; i < 4; ++i) {
                #pragma unroll
                for (int j = 0; j < 8; ++j) {
                    acc[i][j] = fmaf(qv[i].x, kv[j].x, acc[i][j]);
                    acc[i][j] = fmaf(qv[i].y, kv[j].y, acc[i][j]);
                    acc[i][j] = fmaf(qv[i].z, kv[j].z, acc[i][j]);
                    acc[i][j] = fmaf(qv[i].w, kv[j].w, acc[i][j]);
                }
            }
        }

        // Online stats: sum-exp (no max subtraction needed: s ~ N(0,1),
        // exp(s) <= ~1e3 << fp32 range) + branchless sorted top-4 insert.
        #pragma unroll
        for (int i = 0; i < 4; ++i) {
            #pragma unroll
            for (int j = 0; j < 8; ++j) {
                float s  = acc[i][j];
                int  idx = kt * TK + 16 * j + tc;
                Zacc[i] += __expf(s);
                bool c0 = s > tv[i][0];
                bool c1 = s > tv[i][1];
                bool c2 = s > tv[i][2];
                bool c3 = s > tv[i][3];
                tv[i][3] = c2 ? tv[i][2] : (c3 ? s   : tv[i][3]);
                ti[i][3] = c2 ? ti[i][2] : (c3 ? idx : ti[i][3]);
                tv[i][2] = c1 ? tv[i][1] : (c2 ? s   : tv[i][2]);
                ti[i][2] = c1 ? ti[i][1] : (c2 ? idx : ti[i][2]);
                tv[i][1] = c0 ? tv[i][0] : (c1 ? s   : tv[i][1]);
                ti[i][1] = c0 ? ti[i][0] : (c1 ? idx : ti[i][1]);
                tv[i][0] = c0 ? s   : tv[i][0];
                ti[i][0] = c0 ? idx : ti[i][0];
            }
        }

        // Zero-fill this block's (64 rows x 128 keys) slab of dense w.
        // Hidden under compute; kernel B scatters nonzeros afterwards.
        #pragma unroll
        for (int it = 0; it < (TQ * TK) / (4 * 256); ++it) {
            int f = it * 256 + tid;
            int r = f >> 5;
            int c = (f & 31) * 4;
            *reinterpret_cast<float4*>(wb + (size_t)r * L_ + kt * TK + c) =
                make_float4(0.f, 0.f, 0.f, 0.f);
        }
    }

    // Cross-thread merge: 16 lanes (same tr) share each row; they are
    // consecutive lanes within one wave -> width-16 shuffles.
    #pragma unroll
    for (int i = 0; i < 4; ++i) {
        float Z = Zacc[i];
        #pragma unroll
        for (int m = 8; m; m >>= 1) Z += __shfl_xor(Z, m, 16);

        // Tournament top-4 over 16 sorted per-lane lists (argmax with
        // index tie-break => all lanes converge identically).
        int p = 0;
        float mv4[4]; int mi4[4];
        #pragma unroll
        for (int t = 0; t < 4; ++t) {
            float cand  = (p == 0) ? tv[i][0] : (p == 1) ? tv[i][1]
                        : (p == 2) ? tv[i][2] : (p == 3) ? tv[i][3] : -3.0e38f;
            int   candi = (p == 0) ? ti[i][0] : (p == 1) ? ti[i][1]
                        : (p == 2) ? ti[i][2] : (p == 3) ? ti[i][3] : 0x7fffffff;
            float mv = cand; int mi = candi;
            #pragma unroll
            for (int m = 8; m; m >>= 1) {
                float ov = __shfl_xor(mv, m, 16);
                int   oi = __shfl_xor(mi, m, 16);
                if (ov > mv || (ov == mv && oi < mi)) { mv = ov; mi = oi; }
            }
            mv4[t] = mv; mi4[t] = mi;
            if (candi == mi) ++p;   // indices unique -> only winner advances
        }

        // delta = p4 + eps; only top-3 can be positive; renormalize.
        float invZ = 1.0f / Z;
        float p0 = __expf(mv4[0]) * invZ;
        float p1 = __expf(mv4[1]) * invZ;
        float p2 = __expf(mv4[2]) * invZ;
        float p3 = __expf(mv4[3]) * invZ;
        float delta = p3 + 1e-7f;
        float a0 = fmaxf(p0 - delta, 0.f);
        float a1 = fmaxf(p1 - delta, 0.f);
        float a2 = fmaxf(p2 - delta, 0.f);
        float rinv = 1.0f / (a0 + a1 + a2 + 1e-7f);
        if (tc == 0) {
            int gr = b * L_ + row0 + tr * 4 + i;
            *reinterpret_cast<float4*>(wsv + (size_t)gr * 4) =
                make_float4(a0 * rinv, a1 * rinv, a2 * rinv, 0.f);
            *reinterpret_cast<int4*>(wsi + (size_t)gr * 4) =
                make_int4(mi4[0], mi4[1], mi4[2], mi4[3]);
        }
    }
}

// ---------------------------------------------------------------------------
// Kernel B: per row, out = sum_j w_j * v[idx_j] and scatter w nonzeros into
// the (already zero-filled) dense w. 4 rows per 256-thread block, 64 lanes/row.
// ---------------------------------------------------------------------------
__global__ __launch_bounds__(256)
void sdpa_out_scatter(const float* __restrict__ v,
                      const float* __restrict__ wsv,
                      const int*   __restrict__ wsi,
                      float* __restrict__ out,       // [B_*L_*D_]
                      float* __restrict__ wout)      // [B_*L_*L_]
{
    int gr   = blockIdx.x * 4 + (threadIdx.x >> 6);
    int lane = threadIdx.x & 63;
    int b    = gr >> 11;   // / L_

    float4 wv = *reinterpret_cast<const float4*>(wsv + (size_t)gr * 4);
    int4   iv = *reinterpret_cast<const int4*>(wsi + (size_t)gr * 4);

    const float* vb = v + (size_t)b * L_ * D_;
    float o = wv.x * vb[(size_t)iv.x * D_ + lane]
            + wv.y * vb[(size_t)iv.y * D_ + lane]
            + wv.z * vb[(size_t)iv.z * D_ + lane];
    out[(size_t)gr * D_ + lane] = o;

    if (lane < 4) {
        int   si = (lane == 0) ? iv.x : (lane == 1) ? iv.y : (lane == 2) ? iv.z : iv.w;
        float sw = (lane == 0) ? wv.x : (lane == 1) ? wv.y : (lane == 2) ? wv.z : wv.w;
        wout[(size_t)gr * L_ + si] = sw;   // writing 0 at the 4th idx is correct
    }
}

extern "C" void kernel_launch(void* const* d_in, const int* in_sizes, int n_in,
                              void* d_out, int out_size, void* d_ws, size_t ws_size,
                              hipStream_t stream) {
    const float* q = (const float*)d_in[0];
    const float* k = (const float*)d_in[1];
    const float* v = (const float*)d_in[2];

    float* out  = (float*)d_out;                          // [16,2048,64]
    float* wout = out + (size_t)B_ * L_ * D_;             // [16,2048,2048]

    float* wsv = (float*)d_ws;                            // NROWS*4 floats
    int*   wsi = (int*)((float*)d_ws + (size_t)NROWS * 4);// NROWS*4 ints (1 MB total)

    dim3 gridA(L_ / TQ, B_);
    sdpa_score_stats<<<gridA, 256, 0, stream>>>(q, k, wout, wsv, wsi);

    sdpa_out_scatter<<<NROWS / 4, 256, 0, stream>>>(v, wsv, wsi, out, wout);
}

// Round 2
// 137.998 us; speedup vs baseline: 1.7813x; 1.7813x over previous
//
#include <hip/hip_runtime.h>
#include <hip/hip_bf16.h>

// Geometry fixed by reference: B=16, Lq=Lk=2048, D=Dv=64, fp32.
// d_out = out [16,2048,64] ++ w [16,2048,2048].
#define B_ 16
#define L_ 2048
#define D_ 64
#define NROWS (B_ * L_)

typedef _Float16 half8  __attribute__((ext_vector_type(8)));
typedef _Float16 half4v __attribute__((ext_vector_type(4)));
typedef float    f32x4  __attribute__((ext_vector_type(4)));

#define AS1 __attribute__((address_space(1)))
#define AS3 __attribute__((address_space(3)))

__device__ __forceinline__ void gll16(const void* g, void* l) {
    __builtin_amdgcn_global_load_lds((AS1 const unsigned int*)g,
                                     (AS3 unsigned int*)l, 16, 0, 0);
}

// ---------------------------------------------------------------------------
// Kernel P: fp16 hi/lo split conversion.
//   a = q * log2(e)/8 ->  qext = [ah(64), al(64)]  (al = (a-ah)*2048 in fp16)
//   b = k             ->  kext = [bl(64), bh(64)]
// Then score' (log2-domain) = sum ah*bh + 2^-11 * sum([ah,al]·[bl,bh]).
// ---------------------------------------------------------------------------
__global__ __launch_bounds__(256)
void cvt_ext(const float* __restrict__ q, const float* __restrict__ k,
             _Float16* __restrict__ qext, _Float16* __restrict__ kext)
{
    const float CQ = 0.18033688011112042f;   // log2(e)/8
    int i = blockIdx.x * 256 + threadIdx.x;  // quad id over 16*2048*64/4
    int r = i >> 4;
    int d = (i & 15) << 2;

    float4 qv = *reinterpret_cast<const float4*>(q + (size_t)r * D_ + d);
    float4 kv = *reinterpret_cast<const float4*>(k + (size_t)r * D_ + d);

    float a0 = qv.x * CQ, a1 = qv.y * CQ, a2 = qv.z * CQ, a3 = qv.w * CQ;
    half4v ah = { (_Float16)a0, (_Float16)a1, (_Float16)a2, (_Float16)a3 };
    half4v al = { (_Float16)((a0 - (float)ah[0]) * 2048.0f),
                  (_Float16)((a1 - (float)ah[1]) * 2048.0f),
                  (_Float16)((a2 - (float)ah[2]) * 2048.0f),
                  (_Float16)((a3 - (float)ah[3]) * 2048.0f) };
    half4v bh = { (_Float16)kv.x, (_Float16)kv.y, (_Float16)kv.z, (_Float16)kv.w };
    half4v bl = { (_Float16)((kv.x - (float)bh[0]) * 2048.0f),
                  (_Float16)((kv.y - (float)bh[1]) * 2048.0f),
                  (_Float16)((kv.z - (float)bh[2]) * 2048.0f),
                  (_Float16)((kv.w - (float)bh[3]) * 2048.0f) };

    *reinterpret_cast<half4v*>(qext + (size_t)r * 128 + d)      = ah;
    *reinterpret_cast<half4v*>(qext + (size_t)r * 128 + 64 + d) = al;
    *reinterpret_cast<half4v*>(kext + (size_t)r * 128 + d)      = bl;
    *reinterpret_cast<half4v*>(kext + (size_t)r * 128 + 64 + d) = bh;
}

// ---------------------------------------------------------------------------
// Kernel A: MFMA scores + online sum-exp2 + top-4 + interleaved w zero-fill.
// Block = 256 threads (4 waves), 64 q-rows (16/wave), sweeps all 2048 keys in
// 64-key LDS tiles (double buffered, global_load_lds, XOR-swizzled source).
// ---------------------------------------------------------------------------
__global__ __launch_bounds__(256)
void sdpa_mfma(const _Float16* __restrict__ qext,
               const _Float16* __restrict__ kext,
               float* __restrict__ wout,
               float* __restrict__ wsv,
               int*   __restrict__ wsi)
{
    __shared__ __align__(16) _Float16 Qs[64 * 128];
    __shared__ __align__(16) _Float16 Ks[2][64 * 128];

    const int b    = blockIdx.y;
    const int row0 = blockIdx.x * 64;
    const int tid  = threadIdx.x;
    const int w    = tid >> 6;
    const int lane = tid & 63;
    const int c    = lane & 15;    // MFMA col (key) / row lane group pos
    const int g    = lane >> 4;    // k-slot group / row sub-group

    const char* qe = (const char*)(qext + ((size_t)b * L_ + row0) * 128);
    const char* ke = (const char*)(kext + (size_t)b * L_ * 128);
    float* wb = wout + (size_t)b * L_ * L_ + (size_t)row0 * L_;

    // ---- stage Q tile (16 KB, linear) ----
    {
        int off = w * 4096;
        #pragma unroll
        for (int t = 0; t < 4; ++t) {
            int o = off + t * 1024;
            gll16(qe + o + lane * 16, (char*)Qs + o);
        }
    }

    // ---- K-tile staging: LDS linear dest, inverse-swizzled global source.
    // Desired read layout: byte(kl, cb) = kl*256 + ((cb ^ (kl&7))<<4).
    auto stageK = [&](int buf, int kt) {
        const char* src = ke + (size_t)kt * 16384;
        #pragma unroll
        for (int t = 0; t < 4; ++t) {
            int o  = w * 4096 + t * 1024;        // wave-uniform LDS base
            int rr = (o >> 8) + g;               // key row this lane covers
            int gb = rr * 256 + ((c ^ (rr & 7)) << 4);
            gll16(src + gb, (char*)(Ks[buf]) + o);
        }
    };

    stageK(0, 0);
    __syncthreads();   // Q + K0 staged (drains vmcnt then barrier)

    // ---- Q fragments (held in registers for the whole sweep) ----
    const char* qsb = (const char*)Qs;
    const int rowb = (16 * w + c) * 256 + g * 16;
    half8 qf0 = *(const half8*)(qsb + rowb);         // ah, k-cols [0,32)
    half8 qf1 = *(const half8*)(qsb + rowb + 64);    // ah, k-cols [32,64)
    half8 qf2 = *(const half8*)(qsb + rowb + 128);   // al, k-cols [64,96)
    half8 qf3 = *(const half8*)(qsb + rowb + 192);   // al, k-cols [96,128)

    float Zacc[4];
    float tv[4][4];
    int   ti[4][4];
    #pragma unroll
    for (int r = 0; r < 4; ++r) {
        Zacc[r] = 0.0f;
        #pragma unroll
        for (int t = 0; t < 4; ++t) { tv[r][t] = -3.0e38f; ti[r][t] = 0; }
    }

    int buf = 0;
    for (int kt = 0; kt < 32; ++kt) {
        if (kt + 1 < 32) stageK(buf ^ 1, kt + 1);

        // interleaved zero-fill of this block's w slab (64 rows x 64 keys)
        if (b != 15) {
            int zr = tid >> 2;
            int zc = (tid & 3) << 4;
            float* wp = wb + (size_t)zr * L_ + kt * 64 + zc;
            float4 z4 = make_float4(0.f, 0.f, 0.f, 0.f);
            *reinterpret_cast<float4*>(wp + 0)  = z4;
            *reinterpret_cast<float4*>(wp + 4)  = z4;
            *reinterpret_cast<float4*>(wp + 8)  = z4;
            *reinterpret_cast<float4*>(wp + 12) = z4;
        }

        const char* kb = (const char*)(Ks[buf]);
        #pragma unroll
        for (int nt = 0; nt < 4; ++nt) {
            int kl = nt * 16 + c;
            int x  = kl & 7;
            const char* kr = kb + kl * 256;
            half8 bf0 = *(const half8*)(kr + (((0  + g) ^ x) << 4)); // bl [0,32)
            half8 bf1 = *(const half8*)(kr + (((4  + g) ^ x) << 4)); // bl [32,64)
            half8 bf2 = *(const half8*)(kr + (((8  + g) ^ x) << 4)); // bh [0,32)
            half8 bf3 = *(const half8*)(kr + (((12 + g) ^ x) << 4)); // bh [32,64)

            f32x4 a1 = {0.f, 0.f, 0.f, 0.f};
            f32x4 a2 = {0.f, 0.f, 0.f, 0.f};
            a1 = __builtin_amdgcn_mfma_f32_16x16x32_f16(qf0, bf2, a1, 0, 0, 0);
            a2 = __builtin_amdgcn_mfma_f32_16x16x32_f16(qf0, bf0, a2, 0, 0, 0);
            a1 = __builtin_amdgcn_mfma_f32_16x16x32_f16(qf1, bf3, a1, 0, 0, 0);
            a2 = __builtin_amdgcn_mfma_f32_16x16x32_f16(qf1, bf1, a2, 0, 0, 0);
            a2 = __builtin_amdgcn_mfma_f32_16x16x32_f16(qf2, bf2, a2, 0, 0, 0);
            a2 = __builtin_amdgcn_mfma_f32_16x16x32_f16(qf3, bf3, a2, 0, 0, 0);

            const int idx = kt * 64 + nt * 16 + c;
            #pragma unroll
            for (int r = 0; r < 4; ++r) {
                float sp = fmaf(a2[r], 4.8828125e-4f, a1[r]);  // + 2^-11 * lo
                Zacc[r] += exp2f(sp);
                bool c0 = sp > tv[r][0];
                bool c1 = sp > tv[r][1];
                bool c2 = sp > tv[r][2];
                bool c3 = sp > tv[r][3];
                tv[r][3] = c2 ? tv[r][2] : (c3 ? sp  : tv[r][3]);
                ti[r][3] = c2 ? ti[r][2] : (c3 ? idx : ti[r][3]);
                tv[r][2] = c1 ? tv[r][1] : (c2 ? sp  : tv[r][2]);
                ti[r][2] = c1 ? ti[r][1] : (c2 ? idx : ti[r][2]);
                tv[r][1] = c0 ? tv[r][0] : (c1 ? sp  : tv[r][1]);
                ti[r][1] = c0 ? ti[r][0] : (c1 ? idx : ti[r][1]);
                tv[r][0] = c0 ? sp  : tv[r][0];
                ti[r][0] = c0 ? idx : ti[r][0];
            }
        }
        __syncthreads();
        buf ^= 1;
    }

    // ---- per-row merge across the 16 lanes sharing each row ----
    #pragma unroll
    for (int r = 0; r < 4; ++r) {
        float Z = Zacc[r];
        #pragma unroll
        for (int m = 8; m; m >>= 1) Z += __shfl_xor(Z, m, 16);

        int p = 0;
        float mv4[4]; int mi4[4];
        #pragma unroll
        for (int t = 0; t < 4; ++t) {
            float cand  = (p == 0) ? tv[r][0] : (p == 1) ? tv[r][1]
                        : (p == 2) ? tv[r][2] : (p == 3) ? tv[r][3] : -3.0e38f;
            int   candi = (p == 0) ? ti[r][0] : (p == 1) ? ti[r][1]
                        : (p == 2) ? ti[r][2] : (p == 3) ? ti[r][3] : 0x7fffffff;
            float mv = cand; int mi = candi;
            #pragma unroll
            for (int m = 8; m; m >>= 1) {
                float ov = __shfl_xor(mv, m, 16);
                int   oi = __shfl_xor(mi, m, 16);
                if (ov > mv || (ov == mv && oi < mi)) { mv = ov; mi = oi; }
            }
            mv4[t] = mv; mi4[t] = mi;
            if (candi == mi) ++p;
        }

        float invZ = 1.0f / Z;
        float p0 = exp2f(mv4[0]) * invZ;
        float p1 = exp2f(mv4[1]) * invZ;
        float p2 = exp2f(mv4[2]) * invZ;
        float p3 = exp2f(mv4[3]) * invZ;
        float delta = p3 + 1e-7f;
        float a0 = fmaxf(p0 - delta, 0.f);
        float a1 = fmaxf(p1 - delta, 0.f);
        float a2 = fmaxf(p2 - delta, 0.f);
        float rinv = 1.0f / (a0 + a1 + a2 + 1e-7f);
        if (c == 0) {
            int gr = b * L_ + row0 + 16 * w + 4 * g + r;
            *reinterpret_cast<float4*>(wsv + (size_t)gr * 4) =
                make_float4(a0 * rinv, a1 * rinv, a2 * rinv, 0.f);
            *reinterpret_cast<int4*>(wsi + (size_t)gr * 4) =
                make_int4(mi4[0], mi4[1], mi4[2], mi4[3]);
        }
    }
}

// ---------------------------------------------------------------------------
// Kernel B: out = sum_j w_j * v[idx_j]; scatter w nonzeros. Blocks covering
// batch 15 first zero their rows (that slab held the fp16 scratch).
// ---------------------------------------------------------------------------
__global__ __launch_bounds__(256)
void sdpa_out_scatter(const float* __restrict__ v,
                      const float* __restrict__ wsv,
                      const int*   __restrict__ wsi,
                      float* __restrict__ out,
                      float* __restrict__ wout)
{
    int gr0 = blockIdx.x * 4;
    int tid = threadIdx.x;

    if (gr0 >= 15 * L_) {   // block-uniform: scratch region rows
        #pragma unroll
        for (int t = 0; t < 8; ++t) {
            int i  = t * 256 + tid;       // float4 slot 0..2047
            int r  = i >> 9;
            int cc = (i & 511) << 2;
            *reinterpret_cast<float4*>(wout + (size_t)(gr0 + r) * L_ + cc) =
                make_float4(0.f, 0.f, 0.f, 0.f);
        }
        __syncthreads();
    }

    int gr   = gr0 + (tid >> 6);
    int lane = tid & 63;
    int b    = gr >> 11;

    float4 wv = *reinterpret_cast<const float4*>(wsv + (size_t)gr * 4);
    int4   iv = *reinterpret_cast<const int4*>(wsi + (size_t)gr * 4);

    const float* vb = v + (size_t)b * L_ * D_;
    float o = wv.x * vb[(size_t)iv.x * D_ + lane]
            + wv.y * vb[(size_t)iv.y * D_ + lane]
            + wv.z * vb[(size_t)iv.z * D_ + lane];
    out[(size_t)gr * D_ + lane] = o;

    if (lane < 4) {
        int   si = (lane == 0) ? iv.x : (lane == 1) ? iv.y : (lane == 2) ? iv.z : iv.w;
        float sw = (lane == 0) ? wv.x : (lane == 1) ? wv.y : (lane == 2) ? wv.z : wv.w;
        wout[(size_t)gr * L_ + si] = sw;
    }
}

extern "C" void kernel_launch(void* const* d_in, const int* in_sizes, int n_in,
                              void* d_out, int out_size, void* d_ws, size_t ws_size,
                              hipStream_t stream) {
    const float* q = (const float*)d_in[0];
    const float* k = (const float*)d_in[1];
    const float* v = (const float*)d_in[2];

    float* out  = (float*)d_out;
    float* wout = out + (size_t)B_ * L_ * D_;

    // fp16-split scratch lives in w's batch-15 slab (exactly 16.78 MB);
    // kernel B re-zeroes it before scattering.
    _Float16* qext = (_Float16*)(wout + (size_t)15 * L_ * L_);
    _Float16* kext = qext + (size_t)B_ * L_ * 128;

    float* wsv = (float*)d_ws;
    int*   wsi = (int*)((float*)d_ws + (size_t)NROWS * 4);

    cvt_ext<<<(B_ * L_ * D_) / (4 * 256), 256, 0, stream>>>(q, k, qext, kext);

    dim3 gridA(L_ / 64, B_);
    sdpa_mfma<<<gridA, 256, 0, stream>>>(qext, kext, wout, wsv, wsi);

    sdpa_out_scatter<<<NROWS / 4, 256, 0, stream>>>(v, wsv, wsi, out, wout);
}